// Round 1
// baseline (620.341 us; speedup 1.0000x reference)
//
#include <hip/hip_runtime.h>
#include <math.h>

#define N_NODES 50000
#define N_EDGES 800000
#define DOUT 64
#define NHEAD 8
#define RP1 9            // num_relations + 1 (self-loop relation id = 8)
#define NEG_SLOPE 0.2f
#define EPS_F 1e-10f
#define M_TOT (N_EDGES + N_NODES)   // 850000 edges incl. self-loops

// ---------------------------------------------------------------------------
// K1: hidden[r][n][d] = sum_i W[r][d][i] * x[n][i]
// One node per thread; x row held in 64 VGPRs (staged through padded LDS for a
// conflict-free transpose); W indices are wave-uniform -> compiler scalarizes
// to s_load (no LDS pressure on the inner loop). Output row is contiguous per
// thread -> float4 stores.
// ---------------------------------------------------------------------------
__global__ __launch_bounds__(256) void k1_hidden(const float* __restrict__ x,
                                                 const float* __restrict__ W,
                                                 float* __restrict__ hidden) {
    __shared__ float xs[256 * 65];   // pad 65: lane-t row reads are 2-way (free)
    const int r = blockIdx.y;
    const int base = blockIdx.x * 256;
    const int t = threadIdx.x;

    // coalesced tile load [256 x 64] -> padded LDS
    for (int q = t; q < 256 * 64 / 4; q += 256) {
        int flat = q * 4;
        int row = flat >> 6;
        int col = flat & 63;
        int n = base + row;
        float4 v = make_float4(0.f, 0.f, 0.f, 0.f);
        if (n < N_NODES) v = *(const float4*)(x + n * 64 + col);
        float* p = &xs[row * 65 + col];
        p[0] = v.x; p[1] = v.y; p[2] = v.z; p[3] = v.w;
    }
    __syncthreads();

    const int n = base + t;
    if (n >= N_NODES) return;

    float xr[64];
#pragma unroll
    for (int i = 0; i < 64; i++) xr[i] = xs[t * 65 + i];

    const float* Wr = W + r * 64 * 64;          // uniform across wave -> s_load
    float* outp = hidden + ((size_t)r * N_NODES + n) * 64;

    for (int d4 = 0; d4 < 16; d4++) {
        float a0 = 0.f, a1 = 0.f, a2 = 0.f, a3 = 0.f;
#pragma unroll
        for (int i = 0; i < 64; i++) {
            float xi = xr[i];
            a0 += Wr[(d4 * 4 + 0) * 64 + i] * xi;
            a1 += Wr[(d4 * 4 + 1) * 64 + i] * xi;
            a2 += Wr[(d4 * 4 + 2) * 64 + i] * xi;
            a3 += Wr[(d4 * 4 + 3) * 64 + i] * xi;
        }
        float4 o; o.x = a0; o.y = a1; o.z = a2; o.w = a3;
        *(float4*)(outp + d4 * 4) = o;
    }
}

// ---------------------------------------------------------------------------
// K2: per (edge, head): w = leakyrelu(q . interleave(h_in, h_out)),
// p = exp(w)*ew  (segment-max dropped: cancels except via EPS, |w| small).
// Stores p, accumulates per-(dest,head) sums and per-dest counts.
// Thread t -> edge m = blk*32 + t/8, head h = t&7.
// ---------------------------------------------------------------------------
__global__ __launch_bounds__(256) void k2_logits(const float* __restrict__ hidden,
                                                 const float* __restrict__ query,
                                                 const int* __restrict__ node_in,
                                                 const int* __restrict__ node_out,
                                                 const int* __restrict__ relation,
                                                 const float* __restrict__ edge_weight,
                                                 float* __restrict__ pw,
                                                 float* __restrict__ sum_att,
                                                 float* __restrict__ cnt) {
    __shared__ float qs[RP1 * NHEAD * 16];   // 1152 floats
    const int t = threadIdx.x;
    for (int q = t; q < RP1 * NHEAD * 16; q += 256) qs[q] = query[q];
    __syncthreads();

    const int m = blockIdx.x * 32 + (t >> 3);
    const int h = t & 7;
    if (m >= M_TOT) return;

    int vni, vno, vrel; float vew;
    if (m < N_EDGES) {
        vni = node_in[m]; vno = node_out[m]; vrel = relation[m]; vew = edge_weight[m];
    } else {
        vni = vno = m - N_EDGES; vrel = RP1 - 1; vew = 1.0f;
    }

    const float* hi = hidden + ((size_t)vrel * N_NODES + vni) * 64 + h * 8;
    const float* ho = hidden + ((size_t)vrel * N_NODES + vno) * 64 + h * 8;
    const float* q8 = qs + (vrel * NHEAD + h) * 16;

    float w = 0.f;
#pragma unroll
    for (int j = 0; j < 8; j++) w += q8[2 * j] * hi[j] + q8[2 * j + 1] * ho[j];
    w = (w > 0.f) ? w : NEG_SLOPE * w;

    float p = __expf(w) * vew;
    pw[m * 8 + h] = p;                      // fully coalesced: m*8+h == blk*256+t
    atomicAdd(&sum_att[vno * 8 + h], p);
    if (h == 0) atomicAdd(&cnt[vno], 1.0f);
}

// ---------------------------------------------------------------------------
// K3: per (edge, d): att = p / (sum/cnt + eps); out[no][d] += att * h_in[d]
// One wave per edge (d = lane). 54M float atomics -> expected bottleneck,
// replaced by CSR in a later round if rocprof confirms.
// ---------------------------------------------------------------------------
__global__ __launch_bounds__(256) void k3_scatter(const float* __restrict__ hidden,
                                                  const int* __restrict__ node_in,
                                                  const int* __restrict__ node_out,
                                                  const int* __restrict__ relation,
                                                  const float* __restrict__ pw,
                                                  const float* __restrict__ sum_att,
                                                  const float* __restrict__ cnt,
                                                  float* __restrict__ out) {
    const int m = blockIdx.x * 4 + (threadIdx.x >> 6);
    const int d = threadIdx.x & 63;
    if (m >= M_TOT) return;

    int vni, vno, vrel;
    if (m < N_EDGES) {
        vni = node_in[m]; vno = node_out[m]; vrel = relation[m];
    } else {
        vni = vno = m - N_EDGES; vrel = RP1 - 1;
    }

    const int h = d >> 3;
    float p = pw[m * 8 + h];
    float norm = sum_att[vno * 8 + h] / cnt[vno];
    float att = p / (norm + EPS_F);
    float v = hidden[((size_t)vrel * N_NODES + vni) * 64 + d];
    atomicAdd(&out[vno * 64 + d], att * v);
}

// ---------------------------------------------------------------------------
// K4: out = relu(out / cnt)
// ---------------------------------------------------------------------------
__global__ __launch_bounds__(256) void k4_finish(float* __restrict__ out,
                                                 const float* __restrict__ cnt) {
    const int i = blockIdx.x * 256 + threadIdx.x;
    if (i < N_NODES * 64) {
        float v = out[i] / cnt[i >> 6];
        out[i] = (v > 0.f) ? v : 0.f;
    }
}

extern "C" void kernel_launch(void* const* d_in, const int* in_sizes, int n_in,
                              void* d_out, int out_size, void* d_ws, size_t ws_size,
                              hipStream_t stream) {
    const float* x        = (const float*)d_in[0];
    const float* W_tau    = (const float*)d_in[1];
    const float* query    = (const float*)d_in[2];
    const int*   node_in  = (const int*)d_in[3];
    const int*   node_out = (const int*)d_in[4];
    const int*   relation = (const int*)d_in[5];
    const float* edge_w   = (const float*)d_in[6];
    float* out = (float*)d_out;

    char* ws = (char*)d_ws;
    // hidden: 9*50000*64*4      = 115,200,000 B
    // pw:     850000*8*4        =  27,200,000 B
    // sum_att:50000*8*4         =   1,600,000 B
    // cnt:    50000*4           =     200,000 B   (total 144.2 MB)
    float* hidden  = (float*)(ws);
    float* pw      = (float*)(ws + 115200000);
    float* sum_att = (float*)(ws + 142400000);
    float* cnt     = (float*)(ws + 144000000);

    // zero accumulators (sum_att and cnt are contiguous) and output
    hipMemsetAsync(sum_att, 0, 1600000 + 200000, stream);
    hipMemsetAsync(out, 0, (size_t)N_NODES * 64 * sizeof(float), stream);

    dim3 g1((N_NODES + 255) / 256, RP1);
    k1_hidden<<<g1, 256, 0, stream>>>(x, W_tau, hidden);

    k2_logits<<<(M_TOT + 31) / 32, 256, 0, stream>>>(hidden, query, node_in, node_out,
                                                     relation, edge_w, pw, sum_att, cnt);

    k3_scatter<<<(M_TOT + 3) / 4, 256, 0, stream>>>(hidden, node_in, node_out, relation,
                                                    pw, sum_att, cnt, out);

    k4_finish<<<(N_NODES * 64 + 255) / 256, 256, 0, stream>>>(out, cnt);
}

// Round 2
// 551.762 us; speedup vs baseline: 1.1243x; 1.1243x over previous
//
#include <hip/hip_runtime.h>
#include <math.h>

#define N_NODES 50000
#define N_EDGES 800000
#define DOUT 64
#define NHEAD 8
#define RP1 9            // num_relations + 1 (self-loop relation id = 8)
#define NEG_SLOPE 0.2f
#define EPS_F 1e-10f
#define M_TOT (N_EDGES + N_NODES)   // 850000 edges incl. self-loops

// ---------------------------------------------------------------------------
// K1: hidden[r][n][d] = sum_i W[r][d][i] * x[n][i]
// Thread = node. x row in 64 VGPRs (padded-LDS transpose). W wave-uniform ->
// s_load. R1 change: results staged in LDS (stride-65, 2-way bank alias =
// free) then written with a fully coalesced float4 sweep — R0's direct
// stores had 2.6x HBM write amplification (300 MB vs 115 MB).
// ---------------------------------------------------------------------------
__global__ __launch_bounds__(256) void k1_hidden(const float* __restrict__ x,
                                                 const float* __restrict__ W,
                                                 float* __restrict__ hidden) {
    __shared__ float xs[256 * 65];   // reused: x tile in, out tile out
    const int r = blockIdx.y;
    const int base = blockIdx.x * 256;
    const int t = threadIdx.x;

    // coalesced tile load [256 x 64] -> padded LDS
    for (int q = t; q < 256 * 64 / 4; q += 256) {
        int flat = q * 4;
        int row = flat >> 6;
        int col = flat & 63;
        int n = base + row;
        float4 v = make_float4(0.f, 0.f, 0.f, 0.f);
        if (n < N_NODES) v = *(const float4*)(x + n * 64 + col);
        float* p = &xs[row * 65 + col];
        p[0] = v.x; p[1] = v.y; p[2] = v.z; p[3] = v.w;
    }
    __syncthreads();

    const int n = base + t;

    float xr[64];
#pragma unroll
    for (int i = 0; i < 64; i++) xr[i] = xs[t * 65 + i];

    const float* Wr = W + r * 64 * 64;          // uniform across wave -> s_load

    // compute 64 outputs; park them back into xs[t*65 + d]
    // (thread t overwrites exactly the region only thread t reads -> no
    //  barrier needed before the writes)
    if (n < N_NODES) {
        for (int d4 = 0; d4 < 16; d4++) {
            float a0 = 0.f, a1 = 0.f, a2 = 0.f, a3 = 0.f;
#pragma unroll
            for (int i = 0; i < 64; i++) {
                float xi = xr[i];
                a0 += Wr[(d4 * 4 + 0) * 64 + i] * xi;
                a1 += Wr[(d4 * 4 + 1) * 64 + i] * xi;
                a2 += Wr[(d4 * 4 + 2) * 64 + i] * xi;
                a3 += Wr[(d4 * 4 + 3) * 64 + i] * xi;
            }
            float* p = &xs[t * 65 + d4 * 4];    // stride-65 b32 writes: 2-way, free
            p[0] = a0; p[1] = a1; p[2] = a2; p[3] = a3;
        }
    }
    __syncthreads();

    // coalesced float4 store sweep (mirror of the load sweep)
    for (int q = t; q < 256 * 64 / 4; q += 256) {
        int flat = q * 4;
        int row = flat >> 6;
        int col = flat & 63;
        int nn = base + row;
        if (nn < N_NODES) {
            const float* p = &xs[row * 65 + col];
            float4 v; v.x = p[0]; v.y = p[1]; v.z = p[2]; v.w = p[3];
            *(float4*)(hidden + ((size_t)r * N_NODES + nn) * 64 + col) = v;
        }
    }
}

// ---------------------------------------------------------------------------
// K2: per (edge, head): w = leakyrelu(q . interleave(h_in, h_out)),
// p = exp(w)*ew  (segment-max dropped: cancels except via EPS, |w| small).
// Stores p, accumulates per-(dest,head) sums and per-dest counts.
// Thread t -> edge m = blk*32 + t/8, head h = t&7.
// ---------------------------------------------------------------------------
__global__ __launch_bounds__(256) void k2_logits(const float* __restrict__ hidden,
                                                 const float* __restrict__ query,
                                                 const int* __restrict__ node_in,
                                                 const int* __restrict__ node_out,
                                                 const int* __restrict__ relation,
                                                 const float* __restrict__ edge_weight,
                                                 float* __restrict__ pw,
                                                 float* __restrict__ sum_att,
                                                 float* __restrict__ cnt) {
    __shared__ float qs[RP1 * NHEAD * 16];   // 1152 floats
    const int t = threadIdx.x;
    for (int q = t; q < RP1 * NHEAD * 16; q += 256) qs[q] = query[q];
    __syncthreads();

    const int m = blockIdx.x * 32 + (t >> 3);
    const int h = t & 7;
    if (m >= M_TOT) return;

    int vni, vno, vrel; float vew;
    if (m < N_EDGES) {
        vni = node_in[m]; vno = node_out[m]; vrel = relation[m]; vew = edge_weight[m];
    } else {
        vni = vno = m - N_EDGES; vrel = RP1 - 1; vew = 1.0f;
    }

    const float* hi = hidden + ((size_t)vrel * N_NODES + vni) * 64 + h * 8;
    const float* ho = hidden + ((size_t)vrel * N_NODES + vno) * 64 + h * 8;
    const float* q8 = qs + (vrel * NHEAD + h) * 16;

    float w = 0.f;
#pragma unroll
    for (int j = 0; j < 8; j++) w += q8[2 * j] * hi[j] + q8[2 * j + 1] * ho[j];
    w = (w > 0.f) ? w : NEG_SLOPE * w;

    float p = __expf(w) * vew;
    pw[m * 8 + h] = p;                      // fully coalesced: m*8+h == blk*256+t
    atomicAdd(&sum_att[vno * 8 + h], p);
    if (h == 0) atomicAdd(&cnt[vno], 1.0f);
}

// ---------------------------------------------------------------------------
// K3: per (edge, d): att = p / (sum/cnt + eps); out[no][d] += att * h_in[d]
// One wave per edge (d = lane). 54M float atomics -> expected next bottleneck,
// replaced by CSR in a later round if rocprof confirms.
// ---------------------------------------------------------------------------
__global__ __launch_bounds__(256) void k3_scatter(const float* __restrict__ hidden,
                                                  const int* __restrict__ node_in,
                                                  const int* __restrict__ node_out,
                                                  const int* __restrict__ relation,
                                                  const float* __restrict__ pw,
                                                  const float* __restrict__ sum_att,
                                                  const float* __restrict__ cnt,
                                                  float* __restrict__ out) {
    const int m = blockIdx.x * 4 + (threadIdx.x >> 6);
    const int d = threadIdx.x & 63;
    if (m >= M_TOT) return;

    int vni, vno, vrel;
    if (m < N_EDGES) {
        vni = node_in[m]; vno = node_out[m]; vrel = relation[m];
    } else {
        vni = vno = m - N_EDGES; vrel = RP1 - 1;
    }

    const int h = d >> 3;
    float p = pw[m * 8 + h];
    float norm = sum_att[vno * 8 + h] / cnt[vno];
    float att = p / (norm + EPS_F);
    float v = hidden[((size_t)vrel * N_NODES + vni) * 64 + d];
    atomicAdd(&out[vno * 64 + d], att * v);
}

// ---------------------------------------------------------------------------
// K4: out = relu(out / cnt)
// ---------------------------------------------------------------------------
__global__ __launch_bounds__(256) void k4_finish(float* __restrict__ out,
                                                 const float* __restrict__ cnt) {
    const int i = blockIdx.x * 256 + threadIdx.x;
    if (i < N_NODES * 64) {
        float v = out[i] / cnt[i >> 6];
        out[i] = (v > 0.f) ? v : 0.f;
    }
}

extern "C" void kernel_launch(void* const* d_in, const int* in_sizes, int n_in,
                              void* d_out, int out_size, void* d_ws, size_t ws_size,
                              hipStream_t stream) {
    const float* x        = (const float*)d_in[0];
    const float* W_tau    = (const float*)d_in[1];
    const float* query    = (const float*)d_in[2];
    const int*   node_in  = (const int*)d_in[3];
    const int*   node_out = (const int*)d_in[4];
    const int*   relation = (const int*)d_in[5];
    const float* edge_w   = (const float*)d_in[6];
    float* out = (float*)d_out;

    char* ws = (char*)d_ws;
    // hidden: 9*50000*64*4      = 115,200,000 B
    // pw:     850000*8*4        =  27,200,000 B
    // sum_att:50000*8*4         =   1,600,000 B
    // cnt:    50000*4           =     200,000 B   (total 144.2 MB)
    float* hidden  = (float*)(ws);
    float* pw      = (float*)(ws + 115200000);
    float* sum_att = (float*)(ws + 142400000);
    float* cnt     = (float*)(ws + 144000000);

    // zero accumulators (sum_att and cnt are contiguous) and output
    hipMemsetAsync(sum_att, 0, 1600000 + 200000, stream);
    hipMemsetAsync(out, 0, (size_t)N_NODES * 64 * sizeof(float), stream);

    dim3 g1((N_NODES + 255) / 256, RP1);
    k1_hidden<<<g1, 256, 0, stream>>>(x, W_tau, hidden);

    k2_logits<<<(M_TOT + 31) / 32, 256, 0, stream>>>(hidden, query, node_in, node_out,
                                                     relation, edge_w, pw, sum_att, cnt);

    k3_scatter<<<(M_TOT + 3) / 4, 256, 0, stream>>>(hidden, node_in, node_out, relation,
                                                    pw, sum_att, cnt, out);

    k4_finish<<<(N_NODES * 64 + 255) / 256, 256, 0, stream>>>(out, cnt);
}

// Round 3
// 516.497 us; speedup vs baseline: 1.2011x; 1.0683x over previous
//
#include <hip/hip_runtime.h>
#include <math.h>

#define N_NODES 50000
#define N_EDGES 800000
#define DOUT 64
#define NHEAD 8
#define RP1 9            // num_relations + 1 (self-loop relation id = 8)
#define NEG_SLOPE 0.2f
#define EPS_F 1e-10f
#define M_TOT (N_EDGES + N_NODES)   // 850000 edges incl. self-loops

// ===========================================================================
// CSR build: in-degree histogram -> 3-kernel exclusive scan -> position fill
// ===========================================================================
__global__ __launch_bounds__(256) void kcount(const int* __restrict__ node_out,
                                              int* __restrict__ cnt) {
    int m = blockIdx.x * 256 + threadIdx.x;
    if (m >= M_TOT) return;
    int no = (m < N_EDGES) ? node_out[m] : (m - N_EDGES);
    atomicAdd(&cnt[no], 1);
}

// 49 blocks x 256 threads, 4 elems/thread (tile 1024)
__global__ __launch_bounds__(256) void kscan1(const int* __restrict__ cnt,
                                              int* __restrict__ rptr,
                                              int* __restrict__ bsum) {
    __shared__ int sd[256];
    const int t = threadIdx.x, b = blockIdx.x;
    const int i0 = b * 1024 + t * 4;
    int c0 = (i0 + 0 < N_NODES) ? cnt[i0 + 0] : 0;
    int c1 = (i0 + 1 < N_NODES) ? cnt[i0 + 1] : 0;
    int c2 = (i0 + 2 < N_NODES) ? cnt[i0 + 2] : 0;
    int c3 = (i0 + 3 < N_NODES) ? cnt[i0 + 3] : 0;
    int tot = c0 + c1 + c2 + c3;
    sd[t] = tot;
    __syncthreads();
    for (int off = 1; off < 256; off <<= 1) {
        int v = (t >= off) ? sd[t - off] : 0;
        __syncthreads();
        sd[t] += v;
        __syncthreads();
    }
    int excl = sd[t] - tot;
    if (i0 + 0 < N_NODES) rptr[i0 + 0] = excl;
    if (i0 + 1 < N_NODES) rptr[i0 + 1] = excl + c0;
    if (i0 + 2 < N_NODES) rptr[i0 + 2] = excl + c0 + c1;
    if (i0 + 3 < N_NODES) rptr[i0 + 3] = excl + c0 + c1 + c2;
    if (t == 255) bsum[b] = sd[255];
}

// 1 block x 64 threads: exclusive scan of 49 block sums
__global__ __launch_bounds__(64) void kscan2(const int* __restrict__ bsum,
                                             int* __restrict__ boff) {
    __shared__ int sd[64];
    const int t = threadIdx.x;
    int own = (t < 49) ? bsum[t] : 0;
    sd[t] = own;
    __syncthreads();
    for (int off = 1; off < 64; off <<= 1) {
        int v = (t >= off) ? sd[t - off] : 0;
        __syncthreads();
        sd[t] += v;
        __syncthreads();
    }
    if (t < 49) boff[t] = sd[t] - own;
}

// add block offsets; also init cursor = row_ptr and row_ptr[N] = M_TOT
__global__ __launch_bounds__(256) void kscan3(int* __restrict__ rptr,
                                              const int* __restrict__ boff,
                                              int* __restrict__ cursor) {
    const int t = threadIdx.x, b = blockIdx.x;
    const int i0 = b * 1024 + t * 4;
    const int off = boff[b];
#pragma unroll
    for (int k = 0; k < 4; k++) {
        int i = i0 + k;
        if (i < N_NODES) {
            int v = rptr[i] + off;
            rptr[i] = v;
            cursor[i] = v;
        }
    }
    if (b == 0 && t == 0) rptr[N_NODES] = M_TOT;
}

__global__ __launch_bounds__(256) void kfill(const int* __restrict__ node_out,
                                             int* __restrict__ cursor,
                                             int* __restrict__ eidx) {
    int m = blockIdx.x * 256 + threadIdx.x;
    if (m >= M_TOT) return;
    int no = (m < N_EDGES) ? node_out[m] : (m - N_EDGES);
    int pos = atomicAdd(&cursor[no], 1);
    eidx[pos] = m;
}

// ===========================================================================
// K1: hidden[r][n][d] = sum_i W[r][d][i] * x[n][i]
// R2 restructure for occupancy: 64 nodes/block, 4 threads per node (each does
// 16 outputs). LDS 16.6 KB (was 66.5 KB -> 2 blocks/CU -> latency-bound at
// VALUBusy 24%). W stays wave-uniform (dg = t>>6 constant per wave) -> s_load.
// ===========================================================================
__global__ __launch_bounds__(256) void k1_hidden(const float* __restrict__ x,
                                                 const float* __restrict__ W,
                                                 float* __restrict__ hidden) {
    __shared__ float xs[64 * 65];
    const int r = blockIdx.y;
    const int base = blockIdx.x * 64;
    const int t = threadIdx.x;
    const int node_local = t & 63;
    const int dg = t >> 6;            // wave-uniform (0..3)

    // coalesced tile load [64 x 64] -> padded LDS (4 float4 per thread)
    for (int q = t; q < 64 * 64 / 4; q += 256) {
        int flat = q * 4;
        int row = flat >> 6;
        int col = flat & 63;
        int n = base + row;
        float4 v = make_float4(0.f, 0.f, 0.f, 0.f);
        if (n < N_NODES) v = *(const float4*)(x + n * 64 + col);
        float* p = &xs[row * 65 + col];
        p[0] = v.x; p[1] = v.y; p[2] = v.z; p[3] = v.w;
    }
    __syncthreads();

    float xr[64];
#pragma unroll
    for (int i = 0; i < 64; i++) xr[i] = xs[node_local * 65 + i];
    __syncthreads();   // everyone has x in regs; LDS now reusable for output

    const float* Wr = W + r * 64 * 64;   // wave-uniform -> s_load

    // 16 outputs per thread: d = dg*16 + g*4 + {0..3}
#pragma unroll
    for (int g = 0; g < 4; g++) {
        const int d0 = dg * 16 + g * 4;
        float a0 = 0.f, a1 = 0.f, a2 = 0.f, a3 = 0.f;
#pragma unroll
        for (int i = 0; i < 64; i++) {
            float xi = xr[i];
            a0 += Wr[(d0 + 0) * 64 + i] * xi;
            a1 += Wr[(d0 + 1) * 64 + i] * xi;
            a2 += Wr[(d0 + 2) * 64 + i] * xi;
            a3 += Wr[(d0 + 3) * 64 + i] * xi;
        }
        float* p = &xs[node_local * 65 + d0];
        p[0] = a0; p[1] = a1; p[2] = a2; p[3] = a3;
    }
    __syncthreads();

    // coalesced float4 store sweep
    for (int q = t; q < 64 * 64 / 4; q += 256) {
        int flat = q * 4;
        int row = flat >> 6;
        int col = flat & 63;
        int nn = base + row;
        if (nn < N_NODES) {
            const float* p = &xs[row * 65 + col];
            float4 v; v.x = p[0]; v.y = p[1]; v.z = p[2]; v.w = p[3];
            *(float4*)(hidden + ((size_t)r * N_NODES + nn) * 64 + col) = v;
        }
    }
}

// ===========================================================================
// K3G: fused attention + aggregation, gather form (replaces k2+k3+k4).
// Wave = dest node, lane = output dim d (head h=d>>3, elem j=d&7).
// update[d] = relu( scale_h * sum_e p_e * h_in_e[d] ),
//   scale_h = 1/((sum_e p_e / deg + eps) * deg)   [linear -> single pass]
// Own-node rows for all 9 relations cached in LDS (ho). No atomics.
// ===========================================================================
__global__ __launch_bounds__(256) void k3g(const float* __restrict__ hidden,
                                           const float* __restrict__ query,
                                           const int* __restrict__ node_in,
                                           const int* __restrict__ relation,
                                           const float* __restrict__ edge_weight,
                                           const int* __restrict__ rptr,
                                           const int* __restrict__ eidx,
                                           float* __restrict__ out) {
    __shared__ float qs[RP1 * NHEAD * 16];   // 1152
    __shared__ float hos[4 * RP1 * 64];      // per-wave own rows, 9 relations
    const int t = threadIdx.x;
    for (int q = t; q < RP1 * NHEAD * 16; q += 256) qs[q] = query[q];

    const int wid = t >> 6;
    const int lane = t & 63;
    const int n = blockIdx.x * 4 + wid;
    const int h = lane >> 3;
    const int j = lane & 7;

    if (n < N_NODES) {
#pragma unroll
        for (int r = 0; r < RP1; r++)
            hos[wid * (RP1 * 64) + r * 64 + lane] =
                hidden[((size_t)r * N_NODES + n) * 64 + lane];
    }
    __syncthreads();
    if (n >= N_NODES) return;

    const int beg = rptr[n], end = rptr[n + 1];
    const float deg = (float)(end - beg);
    const float* how = &hos[wid * (RP1 * 64)];

    float macc = 0.f, sp = 0.f;

    for (int cb = beg; cb < end; cb += 64) {
        const int cdeg = min(64, end - cb);
        // per-lane edge metadata (coalesced loads)
        int ni_l = n, rel_l = RP1 - 1; float ew_l = 1.f;
        if (lane < cdeg) {
            int m = eidx[cb + lane];
            if (m < N_EDGES) {
                ni_l = node_in[m];
                rel_l = relation[m];
                ew_l = edge_weight[m];
            }
        }
        // software-pipelined row gather
        int ni_e = __shfl(ni_l, 0);
        int rel_e = __shfl(rel_l, 0);
        float hi_nxt = hidden[((size_t)rel_e * N_NODES + ni_e) * 64 + lane];

        for (int e = 0; e < cdeg; e++) {
            float hi = hi_nxt;
            int rel_c = __shfl(rel_l, e);
            float ew_c = __shfl(ew_l, e);
            if (e + 1 < cdeg) {
                int ni_n = __shfl(ni_l, e + 1);
                int rel_n = __shfl(rel_l, e + 1);
                hi_nxt = hidden[((size_t)rel_n * N_NODES + ni_n) * 64 + lane];
            }
            float ho = how[rel_c * 64 + lane];
            float q0 = qs[rel_c * 128 + h * 16 + 2 * j];
            float q1 = qs[rel_c * 128 + h * 16 + 2 * j + 1];
            float wp = q0 * hi + q1 * ho;
            wp += __shfl_xor(wp, 1);
            wp += __shfl_xor(wp, 2);
            wp += __shfl_xor(wp, 4);     // head-wide logit, replicated x8
            float w = (wp > 0.f) ? wp : NEG_SLOPE * wp;
            float p = __expf(w) * ew_c;
            macc += p * hi;
            sp += p;                     // per-head sum (replicated x8)
        }
    }

    const float norm = sp / deg;
    const float scale = 1.f / ((norm + EPS_F) * deg);
    float v = macc * scale;
    out[(size_t)n * 64 + lane] = (v > 0.f) ? v : 0.f;
}

extern "C" void kernel_launch(void* const* d_in, const int* in_sizes, int n_in,
                              void* d_out, int out_size, void* d_ws, size_t ws_size,
                              hipStream_t stream) {
    const float* x        = (const float*)d_in[0];
    const float* W_tau    = (const float*)d_in[1];
    const float* query    = (const float*)d_in[2];
    const int*   node_in  = (const int*)d_in[3];
    const int*   node_out = (const int*)d_in[4];
    const int*   relation = (const int*)d_in[5];
    const float* edge_w   = (const float*)d_in[6];
    float* out = (float*)d_out;

    char* ws = (char*)d_ws;
    // layout (bytes):
    float* hidden = (float*)(ws);                       // 115,200,000
    int*   eidx   = (int*)(ws + 115200000);             //   3,400,000
    int*   cnt    = (int*)(ws + 118600000);             //     200,000 (aliased as cursor)
    int*   rptr   = (int*)(ws + 118800000);             //     200,004
    int*   bsum   = (int*)(ws + 119000064);             //         256
    int*   boff   = (int*)(ws + 119000320);             //         256
    int*   cursor = cnt;                                // counts dead after kscan1

    hipMemsetAsync(cnt, 0, N_NODES * sizeof(int), stream);

    // CSR build
    kcount<<<(M_TOT + 255) / 256, 256, 0, stream>>>(node_out, cnt);
    kscan1<<<49, 256, 0, stream>>>(cnt, rptr, bsum);
    kscan2<<<1, 64, 0, stream>>>(bsum, boff);
    kscan3<<<49, 256, 0, stream>>>(rptr, boff, cursor);
    kfill<<<(M_TOT + 255) / 256, 256, 0, stream>>>(node_out, cursor, eidx);

    // per-relation linear transform
    dim3 g1((N_NODES + 63) / 64, RP1);
    k1_hidden<<<g1, 256, 0, stream>>>(x, W_tau, hidden);

    // fused attention + aggregate + relu
    k3g<<<(N_NODES + 3) / 4, 256, 0, stream>>>(hidden, query, node_in, relation,
                                               edge_w, rptr, eidx, out);
}

// Round 5
// 327.293 us; speedup vs baseline: 1.8954x; 1.5781x over previous
//
#include <hip/hip_runtime.h>
#include <math.h>

#define N_NODES 50000
#define N_EDGES 800000
#define DOUT 64
#define NHEAD 8
#define RP1 9            // num_relations + 1 (self-loop relation id = 8)
#define NEG_SLOPE 0.2f
#define EPS_F 1e-10f
#define M_TOT (N_EDGES + N_NODES)   // 850000 edges incl. self-loops
#define NX (N_NODES * DOUT)         // 3,200,000 x elements
#define NW (RP1 * DOUT * DOUT)      // 36,864 W elements

typedef __attribute__((ext_vector_type(8))) short bf16x8;
typedef __attribute__((ext_vector_type(4))) float f32x4;

__device__ __forceinline__ unsigned short f2bf(float f) {
    unsigned int u = __float_as_uint(f);
    unsigned int r = (u + 0x7FFFu + ((u >> 16) & 1u)) >> 16;   // RNE
    return (unsigned short)r;
}
__device__ __forceinline__ float bf2f(unsigned short s) {
    return __uint_as_float(((unsigned int)s) << 16);
}

// ===========================================================================
// kconv: f32 -> bf16 for x and W (vectorized x4)
// ===========================================================================
__global__ __launch_bounds__(256) void kconv(const float* __restrict__ x,
                                             const float* __restrict__ W,
                                             unsigned short* __restrict__ xb,
                                             unsigned short* __restrict__ Wb) {
    int i = (blockIdx.x * 256 + threadIdx.x) * 4;
    if (i < NX) {
        float4 v = *(const float4*)(x + i);
        ushort4 o; o.x = f2bf(v.x); o.y = f2bf(v.y); o.z = f2bf(v.z); o.w = f2bf(v.w);
        *(ushort4*)(xb + i) = o;
    } else if (i < NX + NW) {
        int j = i - NX;
        float4 v = *(const float4*)(W + j);
        ushort4 o; o.x = f2bf(v.x); o.y = f2bf(v.y); o.z = f2bf(v.z); o.w = f2bf(v.w);
        *(ushort4*)(Wb + j) = o;
    }
}

// ===========================================================================
// CSR build: in-degree histogram -> 3-kernel exclusive scan -> position fill
// ===========================================================================
__global__ __launch_bounds__(256) void kcount(const int* __restrict__ node_out,
                                              int* __restrict__ cnt) {
    int m = blockIdx.x * 256 + threadIdx.x;
    if (m >= M_TOT) return;
    int no = (m < N_EDGES) ? node_out[m] : (m - N_EDGES);
    atomicAdd(&cnt[no], 1);
}

__global__ __launch_bounds__(256) void kscan1(const int* __restrict__ cnt,
                                              int* __restrict__ rptr,
                                              int* __restrict__ bsum) {
    __shared__ int sd[256];
    const int t = threadIdx.x, b = blockIdx.x;
    const int i0 = b * 1024 + t * 4;
    int c0 = (i0 + 0 < N_NODES) ? cnt[i0 + 0] : 0;
    int c1 = (i0 + 1 < N_NODES) ? cnt[i0 + 1] : 0;
    int c2 = (i0 + 2 < N_NODES) ? cnt[i0 + 2] : 0;
    int c3 = (i0 + 3 < N_NODES) ? cnt[i0 + 3] : 0;
    int tot = c0 + c1 + c2 + c3;
    sd[t] = tot;
    __syncthreads();
    for (int off = 1; off < 256; off <<= 1) {
        int v = (t >= off) ? sd[t - off] : 0;
        __syncthreads();
        sd[t] += v;
        __syncthreads();
    }
    int excl = sd[t] - tot;
    if (i0 + 0 < N_NODES) rptr[i0 + 0] = excl;
    if (i0 + 1 < N_NODES) rptr[i0 + 1] = excl + c0;
    if (i0 + 2 < N_NODES) rptr[i0 + 2] = excl + c0 + c1;
    if (i0 + 3 < N_NODES) rptr[i0 + 3] = excl + c0 + c1 + c2;
    if (t == 255) bsum[b] = sd[255];
}

__global__ __launch_bounds__(64) void kscan2(const int* __restrict__ bsum,
                                             int* __restrict__ boff) {
    __shared__ int sd[64];
    const int t = threadIdx.x;
    int own = (t < 49) ? bsum[t] : 0;
    sd[t] = own;
    __syncthreads();
    for (int off = 1; off < 64; off <<= 1) {
        int v = (t >= off) ? sd[t - off] : 0;
        __syncthreads();
        sd[t] += v;
        __syncthreads();
    }
    if (t < 49) boff[t] = sd[t] - own;
}

__global__ __launch_bounds__(256) void kscan3(int* __restrict__ rptr,
                                              const int* __restrict__ boff,
                                              int* __restrict__ cursor) {
    const int t = threadIdx.x, b = blockIdx.x;
    const int i0 = b * 1024 + t * 4;
    const int off = boff[b];
#pragma unroll
    for (int k = 0; k < 4; k++) {
        int i = i0 + k;
        if (i < N_NODES) {
            int v = rptr[i] + off;
            rptr[i] = v;
            cursor[i] = v;
        }
    }
    if (b == 0 && t == 0) rptr[N_NODES] = M_TOT;
}

__global__ __launch_bounds__(256) void kfill(const int* __restrict__ node_out,
                                             int* __restrict__ cursor,
                                             int* __restrict__ eidx) {
    int m = blockIdx.x * 256 + threadIdx.x;
    if (m >= M_TOT) return;
    int no = (m < N_EDGES) ? node_out[m] : (m - N_EDGES);
    int pos = atomicAdd(&cursor[no], 1);
    eidx[pos] = m;
}

// ===========================================================================
// K1 (MFMA): hidden_bf16[r][n][d] = sum_i x[n][i] * W[r][d][i]
// A = x [M=node, K=i], B = W^T [K=i, N=d], 16x16x32_bf16, 2 K-steps, 4 d-tiles.
// Layouts (m89/m97/m120-verified): A[m=lane&15][k=quad*8+j];
// B[k=quad*8+j][n=lane&15] (loaded from W rows = B^T rows, same as m97);
// C col=lane&15 (=n=d), row=quad*4+reg (=m=node). Output staged in LDS
// (row stride 72 shorts, 16B-aligned b128 reads) then coalesced 16B stores.
// ===========================================================================
__global__ __launch_bounds__(256) void k1_mfma(const unsigned short* __restrict__ xb,
                                               const unsigned short* __restrict__ Wb,
                                               unsigned short* __restrict__ hiddenb) {
    __shared__ unsigned short st[4 * 16 * 72];   // 9216 shorts = 18.4 KB... (9 KB)
    const int r = blockIdx.y;
    const int t = threadIdx.x;
    const int wv = t >> 6, lane = t & 63;
    const int quad = lane >> 4, l16 = lane & 15;
    const int base = blockIdx.x * 64 + wv * 16;   // this wave's 16 nodes

    int arow = base + l16;
    if (arow >= N_NODES) arow = N_NODES - 1;      // clamp; stores guarded below
    const bf16x8 a0 = *(const bf16x8*)(xb + (size_t)arow * 64 + quad * 8);
    const bf16x8 a1 = *(const bf16x8*)(xb + (size_t)arow * 64 + quad * 8 + 32);

    const unsigned short* Wr = Wb + r * 4096;
    f32x4 acc[4];
#pragma unroll
    for (int dt = 0; dt < 4; dt++) {
        const bf16x8 b0 = *(const bf16x8*)(Wr + (dt * 16 + l16) * 64 + quad * 8);
        const bf16x8 b1 = *(const bf16x8*)(Wr + (dt * 16 + l16) * 64 + quad * 8 + 32);
        f32x4 c = {0.f, 0.f, 0.f, 0.f};
        c = __builtin_amdgcn_mfma_f32_16x16x32_bf16(a0, b0, c, 0, 0, 0);
        c = __builtin_amdgcn_mfma_f32_16x16x32_bf16(a1, b1, c, 0, 0, 0);
        acc[dt] = c;
    }

    unsigned short* sw = &st[wv * 16 * 72];
#pragma unroll
    for (int dt = 0; dt < 4; dt++) {
#pragma unroll
        for (int v = 0; v < 4; v++) {
            int row = quad * 4 + v;
            int col = dt * 16 + l16;
            sw[row * 72 + col] = f2bf(acc[dt][v]);
        }
    }
    __threadfence_block();   // wave-private LDS region: lgkm drain suffices

#pragma unroll
    for (int q = 0; q < 2; q++) {
        int cid = q * 64 + lane;      // 0..127
        int row = cid >> 3;           // 0..15
        int ch = cid & 7;             // 8-short (16B) chunk
        int n = base + row;
        if (n < N_NODES) {
            bf16x8 v = *(const bf16x8*)(sw + row * 72 + ch * 8);
            *(bf16x8*)(hiddenb + ((size_t)r * N_NODES + n) * 64 + ch * 8) = v;
        }
    }
}

// ===========================================================================
// K2: thread per (edge, head): p = exp(leakyrelu(q . interleave(hi,ho))) * ew
// Fully parallel, no atomics, no cross-lane ops. pw indexed by ORIGINAL edge
// id m: pw[m*8+h] (write coalesced since idx == m*8+h).
// ===========================================================================
__global__ __launch_bounds__(256) void k2_logits(const unsigned short* __restrict__ hiddenb,
                                                 const float* __restrict__ query,
                                                 const int* __restrict__ node_in,
                                                 const int* __restrict__ node_out,
                                                 const int* __restrict__ relation,
                                                 const float* __restrict__ edge_weight,
                                                 float* __restrict__ pw) {
    __shared__ float qs[RP1 * NHEAD * 16];
    const int t = threadIdx.x;
    for (int q = t; q < RP1 * NHEAD * 16; q += 256) qs[q] = query[q];
    __syncthreads();

    const int idx = blockIdx.x * 256 + t;
    const int m = idx >> 3;
    const int h = idx & 7;
    if (m >= M_TOT) return;

    int vni, vno, vrel; float vew;
    if (m < N_EDGES) {
        vni = node_in[m]; vno = node_out[m]; vrel = relation[m]; vew = edge_weight[m];
    } else {
        vni = vno = m - N_EDGES; vrel = RP1 - 1; vew = 1.0f;
    }

    const bf16x8 hiv = *(const bf16x8*)(hiddenb + ((size_t)vrel * N_NODES + vni) * 64 + h * 8);
    const bf16x8 hov = *(const bf16x8*)(hiddenb + ((size_t)vrel * N_NODES + vno) * 64 + h * 8);
    const float* q8 = qs + (vrel * NHEAD + h) * 16;

    float w = 0.f;
#pragma unroll
    for (int j = 0; j < 8; j++) {
        w += q8[2 * j] * bf2f((unsigned short)hiv[j])
           + q8[2 * j + 1] * bf2f((unsigned short)hov[j]);
    }
    w = (w > 0.f) ? w : NEG_SLOPE * w;
    pw[idx] = __expf(w) * vew;     // idx == m*8+h, coalesced
}

// ===========================================================================
// K3: wave per dest node, lane = dim d (head h=d>>3).
// R4 FIX: pw is indexed by ORIGINAL edge id (k2 writes pw[m*8+h]); R3 staged
// pw[(cb+e)*8] as if CSR-position-indexed -> every edge used another edge's
// attention weight (absmax 6.06). Now each valid lane gathers its own edge's
// 8 head-weights pw[m_l*8..+7] into psw[lane*8..].
// hi rows gathered with a 4-deep register-rotated prefetch. Per-edge body:
// 1 LDS read + 2 FMA. update[d] = relu(macc / ((sp/deg + eps) * deg)).
// ===========================================================================
__global__ __launch_bounds__(256) void k3_agg(const unsigned short* __restrict__ hiddenb,
                                              const int* __restrict__ node_in,
                                              const int* __restrict__ relation,
                                              const float* __restrict__ pw,
                                              const int* __restrict__ rptr,
                                              const int* __restrict__ eidx,
                                              float* __restrict__ out) {
    __shared__ float ps[4][64 * 8];   // per-wave p staging (8 KB)
    const int t = threadIdx.x;
    const int wv = t >> 6, lane = t & 63;
    const int h = lane >> 3;
    const int n = blockIdx.x * 4 + wv;
    if (n >= N_NODES) return;

    const int beg = rptr[n], end = rptr[n + 1];
    const float deg = (float)(end - beg);
    float* psw = ps[wv];

    float macc = 0.f, sp = 0.f;

    for (int cb = beg; cb < end; cb += 64) {
        const int cdeg = min(64, end - cb);

        // per-lane edge metadata (coalesced eidx read, gathered meta)
        int ni_l = n, rel_l = RP1 - 1;
        int m_l = 0;
        if (lane < cdeg) {
            m_l = eidx[cb + lane];
            if (m_l < N_EDGES) { ni_l = node_in[m_l]; rel_l = relation[m_l]; }
        }

        // stage this chunk's p values: lane e gathers its edge's 8 heads
        if (lane < cdeg) {
            float4 p0 = *(const float4*)(pw + (size_t)m_l * 8);
            float4 p1 = *(const float4*)(pw + (size_t)m_l * 8 + 4);
            *(float4*)&psw[lane * 8] = p0;
            *(float4*)&psw[lane * 8 + 4] = p1;
        }
        __threadfence_block();   // in-wave LDS RAW: drain lgkm/vm before reads

#define LOADROW(K) bf2f(hiddenb[((size_t)__shfl(rel_l, (K)) * N_NODES + __shfl(ni_l, (K))) * 64 + lane])

        float hr0 = LOADROW(0);
        float hr1 = (1 < cdeg) ? LOADROW(1) : 0.f;
        float hr2 = (2 < cdeg) ? LOADROW(2) : 0.f;
        float hr3 = (3 < cdeg) ? LOADROW(3) : 0.f;

        for (int e0 = 0; e0 < cdeg; e0 += 4) {
            {
                int e = e0;
                float hi = hr0; float p = psw[e * 8 + h];
                if (e + 4 < cdeg) hr0 = LOADROW(e + 4);
                macc += p * hi; sp += p;
            }
            if (e0 + 1 < cdeg) {
                int e = e0 + 1;
                float hi = hr1; float p = psw[e * 8 + h];
                if (e + 4 < cdeg) hr1 = LOADROW(e + 4);
                macc += p * hi; sp += p;
            }
            if (e0 + 2 < cdeg) {
                int e = e0 + 2;
                float hi = hr2; float p = psw[e * 8 + h];
                if (e + 4 < cdeg) hr2 = LOADROW(e + 4);
                macc += p * hi; sp += p;
            }
            if (e0 + 3 < cdeg) {
                int e = e0 + 3;
                float hi = hr3; float p = psw[e * 8 + h];
                if (e + 4 < cdeg) hr3 = LOADROW(e + 4);
                macc += p * hi; sp += p;
            }
        }
#undef LOADROW
    }

    const float scale = 1.f / ((sp / deg + EPS_F) * deg);
    float v = macc * scale;
    out[(size_t)n * 64 + lane] = (v > 0.f) ? v : 0.f;
}

extern "C" void kernel_launch(void* const* d_in, const int* in_sizes, int n_in,
                              void* d_out, int out_size, void* d_ws, size_t ws_size,
                              hipStream_t stream) {
    const float* x        = (const float*)d_in[0];
    const float* W_tau    = (const float*)d_in[1];
    const float* query    = (const float*)d_in[2];
    const int*   node_in  = (const int*)d_in[3];
    const int*   node_out = (const int*)d_in[4];
    const int*   relation = (const int*)d_in[5];
    const float* edge_w   = (const float*)d_in[6];
    float* out = (float*)d_out;

    char* ws = (char*)d_ws;
    unsigned short* hiddenb = (unsigned short*)(ws);                  // 57,600,000
    unsigned short* xb      = (unsigned short*)(ws + 57600000);       //  6,400,000
    unsigned short* Wb      = (unsigned short*)(ws + 64000000);       //     73,728
    float*          pw      = (float*)(ws + 64073728);                // 27,200,000
    int*            eidx    = (int*)(ws + 91273728);                  //  3,400,000
    int*            cnt     = (int*)(ws + 94673728);                  //    200,000
    int*            rptr    = (int*)(ws + 94873728);                  //    200,004
    int*            bsum    = (int*)(ws + 95073744);                  //        256
    int*            boff    = (int*)(ws + 95074000);                  //        256
    int*            cursor  = cnt;   // counts dead after kscan1

    hipMemsetAsync(cnt, 0, N_NODES * sizeof(int), stream);

    // bf16 conversion of x and W
    kconv<<<(NX + NW) / 4 / 256, 256, 0, stream>>>(x, W_tau, xb, Wb);

    // CSR build
    kcount<<<(M_TOT + 255) / 256, 256, 0, stream>>>(node_out, cnt);
    kscan1<<<49, 256, 0, stream>>>(cnt, rptr, bsum);
    kscan2<<<1, 64, 0, stream>>>(bsum, boff);
    kscan3<<<49, 256, 0, stream>>>(rptr, boff, cursor);
    kfill<<<(M_TOT + 255) / 256, 256, 0, stream>>>(node_out, cursor, eidx);

    // per-relation linear transform via MFMA
    dim3 g1((N_NODES + 63) / 64, RP1);
    k1_mfma<<<g1, 256, 0, stream>>>(xb, Wb, hiddenb);

    // per-(edge,head) logits
    k2_logits<<<((M_TOT * 8) + 255) / 256, 256, 0, stream>>>(hiddenb, query, node_in,
                                                             node_out, relation, edge_w, pw);

    // wave-per-node aggregation + relu
    k3_agg<<<(N_NODES + 3) / 4, 256, 0, stream>>>(hiddenb, node_in, relation,
                                                  pw, rptr, eidx, out);
}

// Round 6
// 284.414 us; speedup vs baseline: 2.1811x; 1.1508x over previous
//
#include <hip/hip_runtime.h>
#include <math.h>

#define N_NODES 50000
#define N_EDGES 800000
#define DOUT 64
#define NHEAD 8
#define RP1 9            // num_relations + 1 (self-loop relation id = 8)
#define NEG_SLOPE 0.2f
#define EPS_F 1e-10f
#define M_TOT (N_EDGES + N_NODES)   // 850000 edges incl. self-loops
#define NX (N_NODES * DOUT)         // 3,200,000 x elements
#define NW (RP1 * DOUT * DOUT)      // 36,864 W elements

typedef __attribute__((ext_vector_type(8))) short bf16x8;
typedef __attribute__((ext_vector_type(4))) float f32x4;

__device__ __forceinline__ unsigned short f2bf(float f) {
    unsigned int u = __float_as_uint(f);
    unsigned int r = (u + 0x7FFFu + ((u >> 16) & 1u)) >> 16;   // RNE
    return (unsigned short)r;
}
__device__ __forceinline__ float bf2f(unsigned short s) {
    return __uint_as_float(((unsigned int)s) << 16);
}

// ===========================================================================
// kconv: f32 -> bf16 for x and W (vectorized x4)
// ===========================================================================
__global__ __launch_bounds__(256) void kconv(const float* __restrict__ x,
                                             const float* __restrict__ W,
                                             unsigned short* __restrict__ xb,
                                             unsigned short* __restrict__ Wb) {
    int i = (blockIdx.x * 256 + threadIdx.x) * 4;
    if (i < NX) {
        float4 v = *(const float4*)(x + i);
        ushort4 o; o.x = f2bf(v.x); o.y = f2bf(v.y); o.z = f2bf(v.z); o.w = f2bf(v.w);
        *(ushort4*)(xb + i) = o;
    } else if (i < NX + NW) {
        int j = i - NX;
        float4 v = *(const float4*)(W + j);
        ushort4 o; o.x = f2bf(v.x); o.y = f2bf(v.y); o.z = f2bf(v.z); o.w = f2bf(v.w);
        *(ushort4*)(Wb + j) = o;
    }
}

// ===========================================================================
// CSR build: in-degree histogram -> 3-kernel exclusive scan -> meta fill
// ===========================================================================
__global__ __launch_bounds__(256) void kcount(const int* __restrict__ node_out,
                                              int* __restrict__ cnt) {
    int m = blockIdx.x * 256 + threadIdx.x;
    if (m >= M_TOT) return;
    int no = (m < N_EDGES) ? node_out[m] : (m - N_EDGES);
    atomicAdd(&cnt[no], 1);
}

__global__ __launch_bounds__(256) void kscan1(const int* __restrict__ cnt,
                                              int* __restrict__ rptr,
                                              int* __restrict__ bsum) {
    __shared__ int sd[256];
    const int t = threadIdx.x, b = blockIdx.x;
    const int i0 = b * 1024 + t * 4;
    int c0 = (i0 + 0 < N_NODES) ? cnt[i0 + 0] : 0;
    int c1 = (i0 + 1 < N_NODES) ? cnt[i0 + 1] : 0;
    int c2 = (i0 + 2 < N_NODES) ? cnt[i0 + 2] : 0;
    int c3 = (i0 + 3 < N_NODES) ? cnt[i0 + 3] : 0;
    int tot = c0 + c1 + c2 + c3;
    sd[t] = tot;
    __syncthreads();
    for (int off = 1; off < 256; off <<= 1) {
        int v = (t >= off) ? sd[t - off] : 0;
        __syncthreads();
        sd[t] += v;
        __syncthreads();
    }
    int excl = sd[t] - tot;
    if (i0 + 0 < N_NODES) rptr[i0 + 0] = excl;
    if (i0 + 1 < N_NODES) rptr[i0 + 1] = excl + c0;
    if (i0 + 2 < N_NODES) rptr[i0 + 2] = excl + c0 + c1;
    if (i0 + 3 < N_NODES) rptr[i0 + 3] = excl + c0 + c1 + c2;
    if (t == 255) bsum[b] = sd[255];
}

__global__ __launch_bounds__(64) void kscan2(const int* __restrict__ bsum,
                                             int* __restrict__ boff) {
    __shared__ int sd[64];
    const int t = threadIdx.x;
    int own = (t < 49) ? bsum[t] : 0;
    sd[t] = own;
    __syncthreads();
    for (int off = 1; off < 64; off <<= 1) {
        int v = (t >= off) ? sd[t - off] : 0;
        __syncthreads();
        sd[t] += v;
        __syncthreads();
    }
    if (t < 49) boff[t] = sd[t] - own;
}

__global__ __launch_bounds__(256) void kscan3(int* __restrict__ rptr,
                                              const int* __restrict__ boff,
                                              int* __restrict__ cursor) {
    const int t = threadIdx.x, b = blockIdx.x;
    const int i0 = b * 1024 + t * 4;
    const int off = boff[b];
#pragma unroll
    for (int k = 0; k < 4; k++) {
        int i = i0 + k;
        if (i < N_NODES) {
            int v = rptr[i] + off;
            rptr[i] = v;
            cursor[i] = v;
        }
    }
    if (b == 0 && t == 0) rptr[N_NODES] = M_TOT;
}

// R5: fill writes PRE-PACKED per-edge meta in CSR position order:
// epk[pos] = ni | (rel<<16)  (ni<65536, rel<16), eew[pos] = edge weight.
// k3's per-edge reads become fully coalesced; eidx/node_in/relation/pw
// gathers disappear from the hot kernel.
__global__ __launch_bounds__(256) void kfill(const int* __restrict__ node_out,
                                             const int* __restrict__ node_in,
                                             const int* __restrict__ relation,
                                             const float* __restrict__ edge_weight,
                                             int* __restrict__ cursor,
                                             int* __restrict__ epk,
                                             float* __restrict__ eew) {
    int m = blockIdx.x * 256 + threadIdx.x;
    if (m >= M_TOT) return;
    int no, ni, rl; float ew;
    if (m < N_EDGES) {
        no = node_out[m]; ni = node_in[m]; rl = relation[m]; ew = edge_weight[m];
    } else {
        no = ni = m - N_EDGES; rl = RP1 - 1; ew = 1.0f;
    }
    int pos = atomicAdd(&cursor[no], 1);
    epk[pos] = ni | (rl << 16);
    eew[pos] = ew;
}

// ===========================================================================
// K1 (MFMA): hidden_bf16[r][n][d] = sum_i x[n][i] * W[r][d][i]
// Layouts (m89/m97/m120-verified): A[m=lane&15][k=quad*8+j];
// B[k=quad*8+j][n=lane&15]; C col=lane&15 (=d), row=quad*4+reg (=node).
// Output staged in LDS then coalesced 16B stores.
// ===========================================================================
__global__ __launch_bounds__(256) void k1_mfma(const unsigned short* __restrict__ xb,
                                               const unsigned short* __restrict__ Wb,
                                               unsigned short* __restrict__ hiddenb) {
    __shared__ unsigned short st[4 * 16 * 72];
    const int r = blockIdx.y;
    const int t = threadIdx.x;
    const int wv = t >> 6, lane = t & 63;
    const int quad = lane >> 4, l16 = lane & 15;
    const int base = blockIdx.x * 64 + wv * 16;

    int arow = base + l16;
    if (arow >= N_NODES) arow = N_NODES - 1;
    const bf16x8 a0 = *(const bf16x8*)(xb + (size_t)arow * 64 + quad * 8);
    const bf16x8 a1 = *(const bf16x8*)(xb + (size_t)arow * 64 + quad * 8 + 32);

    const unsigned short* Wr = Wb + r * 4096;
    f32x4 acc[4];
#pragma unroll
    for (int dt = 0; dt < 4; dt++) {
        const bf16x8 b0 = *(const bf16x8*)(Wr + (dt * 16 + l16) * 64 + quad * 8);
        const bf16x8 b1 = *(const bf16x8*)(Wr + (dt * 16 + l16) * 64 + quad * 8 + 32);
        f32x4 c = {0.f, 0.f, 0.f, 0.f};
        c = __builtin_amdgcn_mfma_f32_16x16x32_bf16(a0, b0, c, 0, 0, 0);
        c = __builtin_amdgcn_mfma_f32_16x16x32_bf16(a1, b1, c, 0, 0, 0);
        acc[dt] = c;
    }

    unsigned short* sw = &st[wv * 16 * 72];
#pragma unroll
    for (int dt = 0; dt < 4; dt++) {
#pragma unroll
        for (int v = 0; v < 4; v++) {
            sw[(quad * 4 + v) * 72 + dt * 16 + l16] = f2bf(acc[dt][v]);
        }
    }
    __threadfence_block();   // wave-private LDS region

#pragma unroll
    for (int q = 0; q < 2; q++) {
        int cid = q * 64 + lane;
        int row = cid >> 3;
        int ch = cid & 7;
        int n = base + row;
        if (n < N_NODES) {
            bf16x8 v = *(const bf16x8*)(sw + row * 72 + ch * 8);
            *(bf16x8*)(hiddenb + ((size_t)r * N_NODES + n) * 64 + ch * 8) = v;
        }
    }
}

// ===========================================================================
// K3F (fused, replaces R4's k2+k3): wave = dest node.
// Lane layout for the edge loop: lane = e_lo*8 + h -> 8 edges x 8 heads/pass.
// Each lane loads one 16B head-chunk of its edge's hi row and computes the
// head-dot LOCALLY (no per-edge cross-lane ops). ho-side of the logit is
// separable: bho[rel][h] = sum_j q_odd[rel][h][j]*ho[rel][h*8+j], computed
// once per node. Per-lane accumulators acc[j] (d = h*8+j) and sp (head h)
// are reduced across e_lo (shfl_xor 8/16/32) ONCE at the end.
// p = exp(leakyrelu(dot))*ew ; invalid lane slots carry ew=0 -> contribute 0.
// out[d] = relu(acc / ((sp/deg + eps)*deg)).
// ===========================================================================
__global__ __launch_bounds__(256) void k3_fused(const unsigned short* __restrict__ hiddenb,
                                                const float* __restrict__ query,
                                                const int* __restrict__ epk,
                                                const float* __restrict__ eew,
                                                const int* __restrict__ rptr,
                                                float* __restrict__ out) {
    __shared__ float qe[RP1 * 8 * 8];     // even (hi) coefficients, deinterleaved
    __shared__ float qo[RP1 * 8 * 8];     // odd (ho) coefficients
    __shared__ int2  meta[4][64];         // per-wave staged (pk, ew) per edge slot
    __shared__ float bho[4][RP1 * 8];     // per-wave per-(rel,head) ho-dot

    const int t = threadIdx.x;
    for (int q = t; q < RP1 * 64; q += 256) {
        int j = q & 7, rh = q >> 3;
        qe[q] = query[rh * 16 + 2 * j];
        qo[q] = query[rh * 16 + 2 * j + 1];
    }
    __syncthreads();

    const int wv = t >> 6, lane = t & 63;
    const int n = blockIdx.x * 4 + wv;
    if (n >= N_NODES) return;

    // ---- per-node prologue: bho[rel][h] (d-layout: lane = d) ----
    {
        const int hh = lane >> 3, jj = lane & 7;
#pragma unroll
        for (int r = 0; r < RP1; r++) {
            float hov = bf2f(hiddenb[((size_t)r * N_NODES + n) * 64 + lane]);
            float part = qo[(r * 8 + hh) * 8 + jj] * hov;
            part += __shfl_xor(part, 1);
            part += __shfl_xor(part, 2);
            part += __shfl_xor(part, 4);
            if (jj == 0) bho[wv][r * 8 + hh] = part;
        }
    }
    __threadfence_block();

    const int beg = rptr[n], end = rptr[n + 1];
    const float deg = (float)(end - beg);
    const int e_lo = lane >> 3, h = lane & 7;

    float acc[8] = {0.f, 0.f, 0.f, 0.f, 0.f, 0.f, 0.f, 0.f};
    float sp = 0.f;

    for (int cb = beg; cb < end; cb += 64) {
        const int cdeg = min(64, end - cb);

        // stage meta (coalesced global reads; invalid slots -> ew=0 self row)
        int pk = n | ((RP1 - 1) << 16);
        float w = 0.f;
        if (lane < cdeg) { pk = epk[cb + lane]; w = eew[cb + lane]; }
        int2 mt; mt.x = pk; mt.y = __float_as_int(w);
        meta[wv][lane] = mt;
        __threadfence_block();

        const int npass = (cdeg + 7) >> 3;

        // issue phase: up to 8 row-gathers in flight
        bf16x8 rows[8];
        int relr[8]; float ewr[8];
#pragma unroll
        for (int p = 0; p < 8; p++) {
            if (p < npass) {
                int2 m2 = meta[wv][p * 8 + e_lo];
                int ni = m2.x & 0xffff;
                int rl = m2.x >> 16;
                relr[p] = rl;
                ewr[p] = __int_as_float(m2.y);
                rows[p] = *(const bf16x8*)(hiddenb + ((size_t)(rl * N_NODES + ni)) * 64 + h * 8);
            }
        }

        // consume phase: local head-dot, exp, accumulate
#pragma unroll
        for (int p = 0; p < 8; p++) {
            if (p < npass) {
                const float* qp = &qe[(relr[p] * 8 + h) * 8];
                float hif[8];
#pragma unroll
                for (int j = 0; j < 8; j++) hif[j] = bf2f((unsigned short)rows[p][j]);
                float wp = bho[wv][relr[p] * 8 + h];
#pragma unroll
                for (int j = 0; j < 8; j++) wp += qp[j] * hif[j];
                wp = (wp > 0.f) ? wp : NEG_SLOPE * wp;
                float pa = __expf(wp) * ewr[p];
#pragma unroll
                for (int j = 0; j < 8; j++) acc[j] += pa * hif[j];
                sp += pa;
            }
        }
    }

    // ---- once-per-node cross-lane reduction over e_lo ----
#pragma unroll
    for (int j = 0; j < 8; j++) {
        acc[j] += __shfl_xor(acc[j], 8);
        acc[j] += __shfl_xor(acc[j], 16);
        acc[j] += __shfl_xor(acc[j], 32);
    }
    sp += __shfl_xor(sp, 8);
    sp += __shfl_xor(sp, 16);
    sp += __shfl_xor(sp, 32);

    if (e_lo == 0) {   // lanes 0..7, h = lane: write head h's 8 dims (32B)
        const float scale = 1.f / ((sp / deg + EPS_F) * deg);
        float4 o0, o1;
        float v0 = acc[0] * scale, v1 = acc[1] * scale, v2 = acc[2] * scale, v3 = acc[3] * scale;
        float v4 = acc[4] * scale, v5 = acc[5] * scale, v6 = acc[6] * scale, v7 = acc[7] * scale;
        o0.x = v0 > 0.f ? v0 : 0.f; o0.y = v1 > 0.f ? v1 : 0.f;
        o0.z = v2 > 0.f ? v2 : 0.f; o0.w = v3 > 0.f ? v3 : 0.f;
        o1.x = v4 > 0.f ? v4 : 0.f; o1.y = v5 > 0.f ? v5 : 0.f;
        o1.z = v6 > 0.f ? v6 : 0.f; o1.w = v7 > 0.f ? v7 : 0.f;
        float* op = out + (size_t)n * 64 + h * 8;
        *(float4*)(op) = o0;
        *(float4*)(op + 4) = o1;
    }
}

extern "C" void kernel_launch(void* const* d_in, const int* in_sizes, int n_in,
                              void* d_out, int out_size, void* d_ws, size_t ws_size,
                              hipStream_t stream) {
    const float* x        = (const float*)d_in[0];
    const float* W_tau    = (const float*)d_in[1];
    const float* query    = (const float*)d_in[2];
    const int*   node_in  = (const int*)d_in[3];
    const int*   node_out = (const int*)d_in[4];
    const int*   relation = (const int*)d_in[5];
    const float* edge_w   = (const float*)d_in[6];
    float* out = (float*)d_out;

    char* ws = (char*)d_ws;
    unsigned short* hiddenb = (unsigned short*)(ws);                  // 57,600,000
    unsigned short* xb      = (unsigned short*)(ws + 57600000);       //  6,400,000
    unsigned short* Wb      = (unsigned short*)(ws + 64000000);       //     73,728
    int*            epk     = (int*)(ws + 64073728);                  //  3,400,000
    float*          eew     = (float*)(ws + 67473728);                //  3,400,000
    int*            cnt     = (int*)(ws + 70873728);                  //    200,000
    int*            rptr    = (int*)(ws + 71073728);                  //    200,004
    int*            bsum    = (int*)(ws + 71273744);                  //        256
    int*            boff    = (int*)(ws + 71274000);                  //        256
    int*            cursor  = cnt;   // counts dead after kscan1

    hipMemsetAsync(cnt, 0, N_NODES * sizeof(int), stream);

    // bf16 conversion of x and W
    kconv<<<(NX + NW) / 4 / 256, 256, 0, stream>>>(x, W_tau, xb, Wb);

    // CSR build (positions + pre-packed per-slot meta)
    kcount<<<(M_TOT + 255) / 256, 256, 0, stream>>>(node_out, cnt);
    kscan1<<<49, 256, 0, stream>>>(cnt, rptr, bsum);
    kscan2<<<1, 64, 0, stream>>>(bsum, boff);
    kscan3<<<49, 256, 0, stream>>>(rptr, boff, cursor);
    kfill<<<(M_TOT + 255) / 256, 256, 0, stream>>>(node_out, node_in, relation,
                                                   edge_w, cursor, epk, eew);

    // per-relation linear transform via MFMA
    dim3 g1((N_NODES + 63) / 64, RP1);
    k1_mfma<<<g1, 256, 0, stream>>>(xb, Wb, hiddenb);

    // fused logits + aggregation + relu
    k3_fused<<<(N_NODES + 3) / 4, 256, 0, stream>>>(hiddenb, query, epk, eew,
                                                    rptr, out);
}

// Round 7
// 249.018 us; speedup vs baseline: 2.4912x; 1.1421x over previous
//
#include <hip/hip_runtime.h>
#include <math.h>

#define N_NODES 50000
#define N_EDGES 800000
#define DOUT 64
#define NHEAD 8
#define RP1 9            // num_relations + 1 (self-loop relation id = 8)
#define NEG_SLOPE 0.2f
#define EPS_F 1e-10f
#define M_TOT (N_EDGES + N_NODES)   // 850000 edges incl. self-loops
#define NW (RP1 * DOUT * DOUT)      // 36,864 W elements

typedef __attribute__((ext_vector_type(8))) short bf16x8;
typedef __attribute__((ext_vector_type(4))) float f32x4;

__device__ __forceinline__ unsigned short f2bf(float f) {
    unsigned int u = __float_as_uint(f);
    unsigned int r = (u + 0x7FFFu + ((u >> 16) & 1u)) >> 16;   // RNE
    return (unsigned short)r;
}
__device__ __forceinline__ float bf2f(unsigned short s) {
    return __uint_as_float(((unsigned int)s) << 16);
}

// ===========================================================================
// kcount: in-degree histogram; spare duty: convert W f32->bf16 (first 9216
// global threads, 4 elems each) so kconv dispatch disappears.
// ===========================================================================
__global__ __launch_bounds__(256) void kcount(const int* __restrict__ node_out,
                                              int* __restrict__ cnt,
                                              const float* __restrict__ W,
                                              unsigned short* __restrict__ Wb) {
    int m = blockIdx.x * 256 + threadIdx.x;
    if (m < NW / 4) {
        int i = m * 4;
        float4 v = *(const float4*)(W + i);
        ushort4 o; o.x = f2bf(v.x); o.y = f2bf(v.y); o.z = f2bf(v.z); o.w = f2bf(v.w);
        *(ushort4*)(Wb + i) = o;
    }
    if (m >= M_TOT) return;
    int no = (m < N_EDGES) ? node_out[m] : (m - N_EDGES);
    atomicAdd(&cnt[no], 1);
}

// ===========================================================================
// exclusive scan of cnt (3 kernels) -> rptr, cursor
// ===========================================================================
__global__ __launch_bounds__(256) void kscan1(const int* __restrict__ cnt,
                                              int* __restrict__ rptr,
                                              int* __restrict__ bsum) {
    __shared__ int sd[256];
    const int t = threadIdx.x, b = blockIdx.x;
    const int i0 = b * 1024 + t * 4;
    int c0 = (i0 + 0 < N_NODES) ? cnt[i0 + 0] : 0;
    int c1 = (i0 + 1 < N_NODES) ? cnt[i0 + 1] : 0;
    int c2 = (i0 + 2 < N_NODES) ? cnt[i0 + 2] : 0;
    int c3 = (i0 + 3 < N_NODES) ? cnt[i0 + 3] : 0;
    int tot = c0 + c1 + c2 + c3;
    sd[t] = tot;
    __syncthreads();
    for (int off = 1; off < 256; off <<= 1) {
        int v = (t >= off) ? sd[t - off] : 0;
        __syncthreads();
        sd[t] += v;
        __syncthreads();
    }
    int excl = sd[t] - tot;
    if (i0 + 0 < N_NODES) rptr[i0 + 0] = excl;
    if (i0 + 1 < N_NODES) rptr[i0 + 1] = excl + c0;
    if (i0 + 2 < N_NODES) rptr[i0 + 2] = excl + c0 + c1;
    if (i0 + 3 < N_NODES) rptr[i0 + 3] = excl + c0 + c1 + c2;
    if (t == 255) bsum[b] = sd[255];
}

__global__ __launch_bounds__(64) void kscan2(const int* __restrict__ bsum,
                                             int* __restrict__ boff) {
    __shared__ int sd[64];
    const int t = threadIdx.x;
    int own = (t < 49) ? bsum[t] : 0;
    sd[t] = own;
    __syncthreads();
    for (int off = 1; off < 64; off <<= 1) {
        int v = (t >= off) ? sd[t - off] : 0;
        __syncthreads();
        sd[t] += v;
        __syncthreads();
    }
    if (t < 49) boff[t] = sd[t] - own;
}

__global__ __launch_bounds__(256) void kscan3(int* __restrict__ rptr,
                                              const int* __restrict__ boff,
                                              int* __restrict__ cursor) {
    const int t = threadIdx.x, b = blockIdx.x;
    const int i0 = b * 1024 + t * 4;
    const int off = boff[b];
#pragma unroll
    for (int k = 0; k < 4; k++) {
        int i = i0 + k;
        if (i < N_NODES) {
            int v = rptr[i] + off;
            rptr[i] = v;
            cursor[i] = v;
        }
    }
    if (b == 0 && t == 0) rptr[N_NODES] = M_TOT;
}

// kfill: pre-packed per-edge meta in CSR position order:
// epk[pos] = ni | (rel<<16), eew[pos] = edge weight.
__global__ __launch_bounds__(256) void kfill(const int* __restrict__ node_out,
                                             const int* __restrict__ node_in,
                                             const int* __restrict__ relation,
                                             const float* __restrict__ edge_weight,
                                             int* __restrict__ cursor,
                                             int* __restrict__ epk,
                                             float* __restrict__ eew) {
    int m = blockIdx.x * 256 + threadIdx.x;
    if (m >= M_TOT) return;
    int no, ni, rl; float ew;
    if (m < N_EDGES) {
        no = node_out[m]; ni = node_in[m]; rl = relation[m]; ew = edge_weight[m];
    } else {
        no = ni = m - N_EDGES; rl = RP1 - 1; ew = 1.0f;
    }
    int pos = atomicAdd(&cursor[no], 1);
    epk[pos] = ni | (rl << 16);
    eew[pos] = ew;
}

// ===========================================================================
// K1 v2 (MFMA): one block = 64 nodes x ALL 9 relations. x staged f32 -> LDS
// once, converted in-register to bf16 A-frags; r-loop reloads only B-frags
// (L2-hot broadcast). Saves the 8x re-read of x and the kconv dispatch.
// Layouts (R4/R5-verified): A[m=l16][k=quad*8+j] (a0: k 0..31, a1: k 32..63);
// B row (dt*16+l16) of W^T; C col=l16 (=d), row=quad*4+reg (=node).
// ===========================================================================
__global__ __launch_bounds__(256) void k1_mfma(const float* __restrict__ x,
                                               const unsigned short* __restrict__ Wb,
                                               unsigned short* __restrict__ hiddenb) {
    __shared__ float xs[64 * 68];                // 17.4 KB, pad 68
    __shared__ unsigned short st[4 * 16 * 72];   // 9.2 KB epilogue staging
    const int t = threadIdx.x;
    const int wv = t >> 6, lane = t & 63;
    const int quad = lane >> 4, l16 = lane & 15;
    const int base = blockIdx.x * 64 + wv * 16;

    // coalesced f32 tile load [64 x 64] -> padded LDS
    for (int q = t; q < 64 * 64 / 4; q += 256) {
        int flat = q * 4;
        int row = flat >> 6;
        int col = flat & 63;
        int n = blockIdx.x * 64 + row;
        float4 v = make_float4(0.f, 0.f, 0.f, 0.f);
        if (n < N_NODES) v = *(const float4*)(x + (size_t)n * 64 + col);
        float* p = &xs[row * 68 + col];
        p[0] = v.x; p[1] = v.y; p[2] = v.z; p[3] = v.w;
    }
    __syncthreads();

    // build A-frags in registers (bf16)
    int arowl = wv * 16 + l16;                   // local row 0..63
    bf16x8 a0, a1;
#pragma unroll
    for (int j = 0; j < 8; j++) {
        a0[j] = (short)f2bf(xs[arowl * 68 + quad * 8 + j]);
        a1[j] = (short)f2bf(xs[arowl * 68 + quad * 8 + 32 + j]);
    }

    unsigned short* sw = &st[wv * 16 * 72];

    for (int r = 0; r < RP1; r++) {
        const unsigned short* Wr = Wb + r * 4096;
        f32x4 acc[4];
#pragma unroll
        for (int dt = 0; dt < 4; dt++) {
            const bf16x8 b0 = *(const bf16x8*)(Wr + (dt * 16 + l16) * 64 + quad * 8);
            const bf16x8 b1 = *(const bf16x8*)(Wr + (dt * 16 + l16) * 64 + quad * 8 + 32);
            f32x4 c = {0.f, 0.f, 0.f, 0.f};
            c = __builtin_amdgcn_mfma_f32_16x16x32_bf16(a0, b0, c, 0, 0, 0);
            c = __builtin_amdgcn_mfma_f32_16x16x32_bf16(a1, b1, c, 0, 0, 0);
            acc[dt] = c;
        }
        // wave-private epilogue staging (no block barrier needed)
#pragma unroll
        for (int dt = 0; dt < 4; dt++) {
#pragma unroll
            for (int v = 0; v < 4; v++) {
                sw[(quad * 4 + v) * 72 + dt * 16 + l16] = f2bf(acc[dt][v]);
            }
        }
        __threadfence_block();
#pragma unroll
        for (int q = 0; q < 2; q++) {
            int cid = q * 64 + lane;
            int row = cid >> 3;
            int ch = cid & 7;
            int n = base + row;
            if (n < N_NODES) {
                bf16x8 v = *(const bf16x8*)(sw + row * 72 + ch * 8);
                *(bf16x8*)(hiddenb + ((size_t)r * N_NODES + n) * 64 + ch * 8) = v;
            }
        }
        __threadfence_block();   // drain reads before next relation overwrites sw
    }
}

// ===========================================================================
// K3 v2 (fused): wave = TWO nodes (nA=2P, nB=2P+1), chunk = 32 slots/node.
// Two independent gather chains interleaved per wave -> double MLP vs R5.
// Cheap prologue: lane=(rel,h) loads one 16B chunk, local 8-FMA dot -> bho;
// ZERO shfl in prologue (was 27/node). Edge math unchanged:
// p = exp(leakyrelu(bho[rel][h] + sum_j qe*hi_j)) * ew;
// out[d] = relu(acc_d / ((sp/deg + eps)*deg)). Invalid slots carry ew=0.
// ===========================================================================
__global__ __launch_bounds__(256) void k3_fused2(const unsigned short* __restrict__ hiddenb,
                                                 const float* __restrict__ query,
                                                 const int* __restrict__ epk,
                                                 const float* __restrict__ eew,
                                                 const int* __restrict__ rptr,
                                                 float* __restrict__ out) {
    __shared__ float qe[RP1 * 64];       // even (hi) coefficients
    __shared__ float qo[RP1 * 64];       // odd (ho) coefficients
    __shared__ int2  meta[4][64];        // per-wave: slots [0,32)=A, [32,64)=B
    __shared__ float bho[4][2][72];      // per-wave per-node (rel,head) ho-dot

    const int t = threadIdx.x;
    for (int q = t; q < RP1 * 64; q += 256) {
        int j = q & 7, rh = q >> 3;
        qe[q] = query[rh * 16 + 2 * j];
        qo[q] = query[rh * 16 + 2 * j + 1];
    }
    __syncthreads();

    const int wv = t >> 6, lane = t & 63;
    const int pairi = blockIdx.x * 4 + wv;      // grid sized exactly: always valid
    const int nA = pairi * 2, nB = nA + 1;
    const int e_lo = lane >> 3, h = lane & 7;

    // ---- prologue: bho[rel][h] for both nodes, no shfl ----
    {
        const int prel = lane >> 3, ph = lane & 7;      // rel 0..7
        bf16x8 ra = *(const bf16x8*)(hiddenb + ((size_t)(prel * N_NODES + nA)) * 64 + ph * 8);
        bf16x8 rb = *(const bf16x8*)(hiddenb + ((size_t)(prel * N_NODES + nB)) * 64 + ph * 8);
        bf16x8 r8 = ra;   // init to something valid
        if (lane < 16) {
            int n8 = (lane < 8) ? nA : nB;
            r8 = *(const bf16x8*)(hiddenb + ((size_t)(8 * N_NODES + n8)) * 64 + (lane & 7) * 8);
        }
        const float* qop = &qo[(prel * 8 + ph) * 8];
        float da = 0.f, db = 0.f;
#pragma unroll
        for (int j = 0; j < 8; j++) {
            da += qop[j] * bf2f((unsigned short)ra[j]);
            db += qop[j] * bf2f((unsigned short)rb[j]);
        }
        bho[wv][0][prel * 8 + ph] = da;
        bho[wv][1][prel * 8 + ph] = db;
        if (lane < 16) {
            const float* q8p = &qo[(64 + (lane & 7)) * 8];
            float d8 = 0.f;
#pragma unroll
            for (int j = 0; j < 8; j++) d8 += q8p[j] * bf2f((unsigned short)r8[j]);
            bho[wv][(lane < 8) ? 0 : 1][64 + (lane & 7)] = d8;
        }
    }
    __threadfence_block();

    const int begA = rptr[nA], endA = rptr[nA + 1];
    const int begB = endA, endB = rptr[nB + 1];     // rptr[nB] == endA
    const float degA = (float)(endA - begA), degB = (float)(endB - begB);

    float accA[8] = {0.f, 0.f, 0.f, 0.f, 0.f, 0.f, 0.f, 0.f};
    float accB[8] = {0.f, 0.f, 0.f, 0.f, 0.f, 0.f, 0.f, 0.f};
    float spA = 0.f, spB = 0.f;
    int cbA = begA, cbB = begB;

    while (cbA < endA || cbB < endB) {
        const int cA = min(32, endA - cbA);     // >= 0 (cb never passes end)
        const int cB = min(32, endB - cbB);

        // stage meta: lanes 0..31 -> A slots, 32..63 -> B slots
        int pk = nA | ((RP1 - 1) << 16);        // dummy: valid row, ew=0
        float w = 0.f;
        if (lane < 32) {
            if (lane < cA) { pk = epk[cbA + lane]; w = eew[cbA + lane]; }
        } else {
            int l2 = lane - 32;
            if (l2 < cB) { pk = epk[cbB + l2]; w = eew[cbB + l2]; }
        }
        int2 mt; mt.x = pk; mt.y = __float_as_int(w);
        meta[wv][lane] = mt;
        __threadfence_block();

        const int npA = (cA + 7) >> 3, npB = (cB + 7) >> 3;

        // issue phase: interleave A and B gathers (up to 8 in flight)
        bf16x8 rA[4], rB[4];
        int relA[4], relB[4]; float ewA[4], ewB[4];
#pragma unroll
        for (int p = 0; p < 4; p++) {
            if (p < npA) {
                int2 m2 = meta[wv][p * 8 + e_lo];
                int ni = m2.x & 0xffff, rl = m2.x >> 16;
                relA[p] = rl; ewA[p] = __int_as_float(m2.y);
                rA[p] = *(const bf16x8*)(hiddenb + ((size_t)(rl * N_NODES + ni)) * 64 + h * 8);
            }
            if (p < npB) {
                int2 m2 = meta[wv][32 + p * 8 + e_lo];
                int ni = m2.x & 0xffff, rl = m2.x >> 16;
                relB[p] = rl; ewB[p] = __int_as_float(m2.y);
                rB[p] = *(const bf16x8*)(hiddenb + ((size_t)(rl * N_NODES + ni)) * 64 + h * 8);
            }
        }

        // consume phase
#pragma unroll
        for (int p = 0; p < 4; p++) {
            if (p < npA) {
                const float* qp = &qe[(relA[p] * 8 + h) * 8];
                float hif[8];
#pragma unroll
                for (int j = 0; j < 8; j++) hif[j] = bf2f((unsigned short)rA[p][j]);
                float wp = bho[wv][0][relA[p] * 8 + h];
#pragma unroll
                for (int j = 0; j < 8; j++) wp += qp[j] * hif[j];
                wp = (wp > 0.f) ? wp : NEG_SLOPE * wp;
                float pa = __expf(wp) * ewA[p];
#pragma unroll
                for (int j = 0; j < 8; j++) accA[j] += pa * hif[j];
                spA += pa;
            }
            if (p < npB) {
                const float* qp = &qe[(relB[p] * 8 + h) * 8];
                float hif[8];
#pragma unroll
                for (int j = 0; j < 8; j++) hif[j] = bf2f((unsigned short)rB[p][j]);
                float wp = bho[wv][1][relB[p] * 8 + h];
#pragma unroll
                for (int j = 0; j < 8; j++) wp += qp[j] * hif[j];
                wp = (wp > 0.f) ? wp : NEG_SLOPE * wp;
                float pa = __expf(wp) * ewB[p];
#pragma unroll
                for (int j = 0; j < 8; j++) accB[j] += pa * hif[j];
                spB += pa;
            }
        }

        cbA += cA; cbB += cB;
    }

    // ---- once-per-pair butterfly reduction over e_lo (allreduce) ----
#pragma unroll
    for (int j = 0; j < 8; j++) {
        accA[j] += __shfl_xor(accA[j], 8);
        accA[j] += __shfl_xor(accA[j], 16);
        accA[j] += __shfl_xor(accA[j], 32);
        accB[j] += __shfl_xor(accB[j], 8);
        accB[j] += __shfl_xor(accB[j], 16);
        accB[j] += __shfl_xor(accB[j], 32);
    }
    spA += __shfl_xor(spA, 8); spA += __shfl_xor(spA, 16); spA += __shfl_xor(spA, 32);
    spB += __shfl_xor(spB, 8); spB += __shfl_xor(spB, 16); spB += __shfl_xor(spB, 32);

    if (lane < 8) {                 // write A: h = lane
        const float s = 1.f / ((spA / degA + EPS_F) * degA);
        float4 o0, o1;
        o0.x = fmaxf(accA[0] * s, 0.f); o0.y = fmaxf(accA[1] * s, 0.f);
        o0.z = fmaxf(accA[2] * s, 0.f); o0.w = fmaxf(accA[3] * s, 0.f);
        o1.x = fmaxf(accA[4] * s, 0.f); o1.y = fmaxf(accA[5] * s, 0.f);
        o1.z = fmaxf(accA[6] * s, 0.f); o1.w = fmaxf(accA[7] * s, 0.f);
        float* op = out + (size_t)nA * 64 + lane * 8;
        *(float4*)(op) = o0; *(float4*)(op + 4) = o1;
    } else if (lane < 16) {         // write B: h = lane-8
        const float s = 1.f / ((spB / degB + EPS_F) * degB);
        float4 o0, o1;
        o0.x = fmaxf(accB[0] * s, 0.f); o0.y = fmaxf(accB[1] * s, 0.f);
        o0.z = fmaxf(accB[2] * s, 0.f); o0.w = fmaxf(accB[3] * s, 0.f);
        o1.x = fmaxf(accB[4] * s, 0.f); o1.y = fmaxf(accB[5] * s, 0.f);
        o1.z = fmaxf(accB[6] * s, 0.f); o1.w = fmaxf(accB[7] * s, 0.f);
        float* op = out + (size_t)nB * 64 + (lane - 8) * 8;
        *(float4*)(op) = o0; *(float4*)(op + 4) = o1;
    }
}

extern "C" void kernel_launch(void* const* d_in, const int* in_sizes, int n_in,
                              void* d_out, int out_size, void* d_ws, size_t ws_size,
                              hipStream_t stream) {
    const float* x        = (const float*)d_in[0];
    const float* W_tau    = (const float*)d_in[1];
    const float* query    = (const float*)d_in[2];
    const int*   node_in  = (const int*)d_in[3];
    const int*   node_out = (const int*)d_in[4];
    const int*   relation = (const int*)d_in[5];
    const float* edge_w   = (const float*)d_in[6];
    float* out = (float*)d_out;

    char* ws = (char*)d_ws;
    unsigned short* hiddenb = (unsigned short*)(ws);                  // 57,600,000
    unsigned short* Wb      = (unsigned short*)(ws + 57600000);       //     73,728
    int*            epk     = (int*)(ws + 57673728);                  //  3,400,000
    float*          eew     = (float*)(ws + 61073728);                //  3,400,000
    int*            cnt     = (int*)(ws + 64473728);                  //    200,000
    int*            rptr    = (int*)(ws + 64673728);                  //    200,004
    int*            bsum    = (int*)(ws + 64873732);                  //        256
    int*            boff    = (int*)(ws + 64873988);                  //        256
    int*            cursor  = cnt;   // counts dead after kscan1

    hipMemsetAsync(cnt, 0, N_NODES * sizeof(int), stream);

    // CSR build (kcount also converts W f32->bf16)
    kcount<<<(M_TOT + 255) / 256, 256, 0, stream>>>(node_out, cnt, W_tau, Wb);
    kscan1<<<49, 256, 0, stream>>>(cnt, rptr, bsum);
    kscan2<<<1, 64, 0, stream>>>(bsum, boff);
    kscan3<<<49, 256, 0, stream>>>(rptr, boff, cursor);
    kfill<<<(M_TOT + 255) / 256, 256, 0, stream>>>(node_out, node_in, relation,
                                                   edge_w, cursor, epk, eew);

    // per-relation linear transform via MFMA (all 9 relations per block)
    k1_mfma<<<(N_NODES + 63) / 64, 256, 0, stream>>>(x, Wb, hiddenb);

    // fused logits + aggregation + relu (2 nodes per wave)
    k3_fused2<<<(N_NODES / 2 + 3) / 4, 256, 0, stream>>>(hiddenb, query, epk, eew,
                                                         rptr, out);
}